// Round 6
// baseline (60.384 us; speedup 1.0000x reference)
//
#include <hip/hip_runtime.h>

#define N 16384
#define K_ACTIVE 50
#define MAT_BIT (1 << 14)
#define NBINS 256
#define NCOPIES 32

// ws layout:
//   [0, 256)    : int hdr (hdr[0] = clamped active-column count)
//   [256, +64K) : float y[N]
//   [+32K)      : int ghist[NBINS][NCOPIES]   (transposed for int4 summing)
//   [+128K)     : int list[2N] (bit14 selects w_rec)

// Single block. Zero ghist; append active columns via LDS-atomic (order
// arbitrary -- output-invariant: y is an exact order-independent sum of 1.0f,
// and all later stages depend only on y).
__global__ void __launch_bounds__(1024) build_all(const float* __restrict__ x,
                                                  const float* __restrict__ yl,
                                                  int* __restrict__ hdr,
                                                  int* __restrict__ list,
                                                  int* __restrict__ ghist,
                                                  int cap) {
    __shared__ int lcnt;
    const int tid = threadIdx.x;
    if (tid == 0) lcnt = 0;
    for (int i = tid; i < NCOPIES * NBINS; i += 1024) ghist[i] = 0;
    __syncthreads();

    const int base = tid * 16;
    #pragma unroll
    for (int i = 0; i < 4; ++i) {
        float4 a = *(const float4*)(x + base + i * 4);
        float4 b = *(const float4*)(yl + base + i * 4);
        float av[4] = {a.x, a.y, a.z, a.w};
        float bv[4] = {b.x, b.y, b.z, b.w};
        #pragma unroll
        for (int j = 0; j < 4; ++j) {
            if (av[j] > 0.5f) {
                int s = atomicAdd(&lcnt, 1);
                if (s < cap) list[s] = base + i * 4 + j;
            }
            if (bv[j] > 0.5f) {
                int s = atomicAdd(&lcnt, 1);
                if (s < cap) list[s] = (base + i * 4 + j) | MAT_BIT;
            }
        }
    }
    __syncthreads();
    if (tid == 0) hdr[0] = (lcnt < cap) ? lcnt : cap;
}

// 2048 blocks x 256 threads (32 waves/CU) -- R4 measured-best config.
// Each wave gathers 2 rows (4 independent scattered loads in flight/lane).
// Per-block LDS histogram -> 32 transposed global copies.
// [MSHR-floor: ~6400 lines/CU at ~14 cy/line; RPW=4 measured null (R5).]
__global__ void __launch_bounds__(256) spmv_hist(const float* __restrict__ w_in,
                                                 const float* __restrict__ w_rec,
                                                 const int* __restrict__ hdr,
                                                 const int* __restrict__ list,
                                                 float* __restrict__ y,
                                                 int* __restrict__ ghist) {
    __shared__ int hist[NBINS];
    const int tid = threadIdx.x;
    hist[tid] = 0;   // BLOCK == NBINS
    const int lane = tid & 63;
    const int wid = tid >> 6;
    const int row0 = blockIdx.x * 8 + wid * 2;
    const size_t off0 = (size_t)row0 * N;
    const int n = hdr[0];

    float s0 = 0.f, s1 = 0.f;
    if (lane < n) {
        int enc = list[lane];
        const float* b = (enc & MAT_BIT) ? w_rec : w_in;
        size_t a = off0 + (size_t)(enc & (N - 1));
        s0 += b[a];
        s1 += b[a + N];
    }
    if (lane + 64 < n) {
        int enc = list[lane + 64];
        const float* b = (enc & MAT_BIT) ? w_rec : w_in;
        size_t a = off0 + (size_t)(enc & (N - 1));
        s0 += b[a];
        s1 += b[a + N];
    }
    for (int e = 128 + lane; e < n; e += 64) {   // rare tail
        int enc = list[e];
        const float* b = (enc & MAT_BIT) ? w_rec : w_in;
        size_t a = off0 + (size_t)(enc & (N - 1));
        s0 += b[a];
        s1 += b[a + N];
    }
    #pragma unroll
    for (int off = 32; off >= 1; off >>= 1) {
        s0 += __shfl_xor(s0, off, 64);
        s1 += __shfl_xor(s1, off, 64);
    }
    __syncthreads();   // hist zeroing complete
    if (lane == 0) {
        y[row0] = s0;
        y[row0 + 1] = s1;
        atomicAdd(&hist[min(max((int)s0, 0), NBINS - 1)], 1);
        atomicAdd(&hist[min(max((int)s1, 0), NBINS - 1)], 1);
    }
    __syncthreads();
    {
        int c = hist[tid];
        if (c) atomicAdd(&ghist[tid * NCOPIES + (blockIdx.x & (NCOPIES - 1))], c);
    }
}

// Single block, 256 threads (4 waves -- cheap barriers). Threshold via a
// single-wave shuffle suffix-scan (zero barriers); stable lowest-index-first
// tie-break (matching jax.lax.top_k) with a two-level shuffle scan. y is read
// twice (second read L1/L2-hot) to avoid 64 bins/thread in registers.
__global__ void __launch_bounds__(256) finalize(const float* __restrict__ y,
                                                const int* __restrict__ ghist,
                                                float* __restrict__ out) {
    __shared__ int shist[NBINS];
    __shared__ int wsum[4];
    __shared__ int s_t, s_need;
    const int tid = threadIdx.x;
    const int lane = tid & 63;
    const int wid = tid >> 6;

    {   // sum the 32 transposed copies for my bin
        const int4* g = (const int4*)(ghist + tid * NCOPIES);
        int s = 0;
        #pragma unroll
        for (int i = 0; i < NCOPIES / 4; ++i) {
            int4 v = g[i];
            s += v.x + v.y + v.z + v.w;
        }
        shist[tid] = s;
    }
    __syncthreads();

    // wave 0: suffix scan over 256 bins, 4 bins/lane, shuffles only
    if (wid == 0) {
        int4 b = *(const int4*)(shist + lane * 4);
        int s3 = b.w;
        int s2 = b.z + s3;
        int s1 = b.y + s2;
        int s0 = b.x + s1;           // lane-local inclusive suffix sums
        int T = s0;
        int acc = T;
        #pragma unroll
        for (int off = 1; off < 64; off <<= 1) {
            int v = __shfl_down(acc, off, 64);
            if (lane + off < 64) acc += v;
        }
        int above = acc - T;          // sum over bins >= 4*(lane+1)
        int c[4]  = {s0 + above, s1 + above, s2 + above, s3 + above};
        int cn[4] = {s1 + above, s2 + above, s3 + above, above};
        #pragma unroll
        for (int k = 0; k < 4; ++k) {
            if (c[k] >= K_ACTIVE && cn[k] < K_ACTIVE) {
                s_t = lane * 4 + k;           // exactly one (lane,k) matches
                s_need = K_ACTIVE - cn[k];
            }
        }
    }
    __syncthreads();
    const int t = s_t, need = s_need;

    // pass 1: count ties in my contiguous 64-row chunk
    const int base = tid * 64;
    int c = 0;
    for (int i = 0; i < 64; i += 4) {
        float4 v = *(const float4*)(y + base + i);
        c += (min((int)v.x, NBINS - 1) == t) + (min((int)v.y, NBINS - 1) == t) +
             (min((int)v.z, NBINS - 1) == t) + (min((int)v.w, NBINS - 1) == t);
    }
    // two-level scan: wave shuffle + 4 wave sums
    int inc = c;
    #pragma unroll
    for (int off = 1; off < 64; off <<= 1) {
        int v = __shfl_up(inc, off, 64);
        if (lane >= off) inc += v;
    }
    if (lane == 63) wsum[wid] = inc;
    __syncthreads();
    int run = inc - c;
    #pragma unroll
    for (int w = 0; w < 4; ++w) run += (w < wid) ? wsum[w] : 0;

    // pass 2: re-read (cache-hot), emit 0/1 with stable tie budget
    for (int i = 0; i < 64; i += 4) {
        float4 v = *(const float4*)(y + base + i);
        int b[4] = {min((int)v.x, NBINS - 1), min((int)v.y, NBINS - 1),
                    min((int)v.z, NBINS - 1), min((int)v.w, NBINS - 1)};
        float o[4];
        #pragma unroll
        for (int j = 0; j < 4; ++j) {
            float r = 0.f;
            if (b[j] > t) r = 1.f;
            else if (b[j] == t) { if (run < need) r = 1.f; run++; }
            o[j] = r;
        }
        *(float4*)(out + base + i) = make_float4(o[0], o[1], o[2], o[3]);
    }
}

extern "C" void kernel_launch(void* const* d_in, const int* in_sizes, int n_in,
                              void* d_out, int out_size, void* d_ws, size_t ws_size,
                              hipStream_t stream) {
    const float* x     = (const float*)d_in[0];
    const float* ylat  = (const float*)d_in[1];
    const float* w_in  = (const float*)d_in[2];
    const float* w_rec = (const float*)d_in[3];
    float* out = (float*)d_out;

    char* ws = (char*)d_ws;
    int*   hdr   = (int*)ws;
    float* y     = (float*)(ws + 256);
    int*   ghist = (int*)(ws + 256 + (size_t)N * sizeof(float));
    int*   list  = (int*)(ws + 256 + (size_t)N * sizeof(float)
                          + (size_t)NCOPIES * NBINS * sizeof(int));
    size_t used = 256 + (size_t)N * sizeof(float) + (size_t)NCOPIES * NBINS * sizeof(int);
    long long cap_ll = (ws_size > used) ? (long long)((ws_size - used) / sizeof(int)) : 0;
    int cap = (cap_ll > 2LL * N) ? 2 * N : (int)cap_ll;

    build_all<<<1, 1024, 0, stream>>>(x, ylat, hdr, list, ghist, cap);
    spmv_hist<<<N / 8, 256, 0, stream>>>(w_in, w_rec, hdr, list, y, ghist);
    finalize<<<1, 256, 0, stream>>>(y, ghist, out);
}

// Round 7
// 49.658 us; speedup vs baseline: 1.2160x; 1.2160x over previous
//
#include <hip/hip_runtime.h>

#define N 16384
#define K_ACTIVE 50
#define MAT_BIT (1 << 14)
#define NBINS 256
#define NCOPIES 32

// ws layout:
//   [0, 256)    : int hdr (hdr[0] = clamped active-column count)
//   [256, +64K) : float y[N]
//   [+32K)      : int ghist[NCOPIES][NBINS]
//   [+128K)     : int list[2N] (bit14 selects w_rec)

// Single block. Zero ghist; append active columns via LDS-atomic (order
// arbitrary -- output-invariant: y is an exact order-independent sum of 1.0f,
// and all later stages depend only on y).  [R4 measured-good, verbatim]
__global__ void __launch_bounds__(1024) build_all(const float* __restrict__ x,
                                                  const float* __restrict__ yl,
                                                  int* __restrict__ hdr,
                                                  int* __restrict__ list,
                                                  int* __restrict__ ghist,
                                                  int cap) {
    __shared__ int lcnt;
    const int tid = threadIdx.x;
    if (tid == 0) lcnt = 0;
    for (int i = tid; i < NCOPIES * NBINS; i += 1024) ghist[i] = 0;
    __syncthreads();

    const int base = tid * 16;
    #pragma unroll
    for (int i = 0; i < 4; ++i) {
        float4 a = *(const float4*)(x + base + i * 4);
        float4 b = *(const float4*)(yl + base + i * 4);
        float av[4] = {a.x, a.y, a.z, a.w};
        float bv[4] = {b.x, b.y, b.z, b.w};
        #pragma unroll
        for (int j = 0; j < 4; ++j) {
            if (av[j] > 0.5f) {
                int s = atomicAdd(&lcnt, 1);
                if (s < cap) list[s] = base + i * 4 + j;
            }
            if (bv[j] > 0.5f) {
                int s = atomicAdd(&lcnt, 1);
                if (s < cap) list[s] = (base + i * 4 + j) | MAT_BIT;
            }
        }
    }
    __syncthreads();
    if (tid == 0) hdr[0] = (lcnt < cap) ? lcnt : cap;
}

// 2048 blocks x 256 threads (32 waves/CU) -- R4 measured-best, verbatim.
// Each wave gathers 2 rows (4 independent scattered loads in flight/lane).
// [MSHR-floor: ~6400 lines/CU; RPW=4 measured null (R5); last-block-done
//  fusion measured toxic (R3: per-block device fences on multi-XCD CDNA).]
__global__ void __launch_bounds__(256) spmv_hist(const float* __restrict__ w_in,
                                                 const float* __restrict__ w_rec,
                                                 const int* __restrict__ hdr,
                                                 const int* __restrict__ list,
                                                 float* __restrict__ y,
                                                 int* __restrict__ ghist) {
    __shared__ int hist[NBINS];
    const int tid = threadIdx.x;
    if (tid < NBINS) hist[tid] = 0;
    const int lane = tid & 63;
    const int wid = tid >> 6;
    const int row0 = blockIdx.x * 8 + wid * 2;
    const size_t off0 = (size_t)row0 * N;
    const int n = hdr[0];

    float s0 = 0.f, s1 = 0.f;
    if (lane < n) {
        int enc = list[lane];
        const float* b = (enc & MAT_BIT) ? w_rec : w_in;
        size_t a = off0 + (size_t)(enc & (N - 1));
        s0 += b[a];
        s1 += b[a + N];
    }
    if (lane + 64 < n) {
        int enc = list[lane + 64];
        const float* b = (enc & MAT_BIT) ? w_rec : w_in;
        size_t a = off0 + (size_t)(enc & (N - 1));
        s0 += b[a];
        s1 += b[a + N];
    }
    for (int e = 128 + lane; e < n; e += 64) {   // rare tail
        int enc = list[e];
        const float* b = (enc & MAT_BIT) ? w_rec : w_in;
        size_t a = off0 + (size_t)(enc & (N - 1));
        s0 += b[a];
        s1 += b[a + N];
    }
    #pragma unroll
    for (int off = 32; off >= 1; off >>= 1) {
        s0 += __shfl_xor(s0, off, 64);
        s1 += __shfl_xor(s1, off, 64);
    }
    __syncthreads();   // hist zeroing complete
    if (lane == 0) {
        y[row0] = s0;
        y[row0 + 1] = s1;
        atomicAdd(&hist[min(max((int)s0, 0), NBINS - 1)], 1);
        atomicAdd(&hist[min(max((int)s1, 0), NBINS - 1)], 1);
    }
    __syncthreads();
    if (tid < NBINS) {
        int c = hist[tid];
        if (c) atomicAdd(&ghist[(blockIdx.x & (NCOPIES - 1)) * NBINS + tid], c);
    }
}

// Single block, 1024 threads. R4-verbatim EXCEPT: the y reads are hoisted to
// the very top so their ~3us of L3 latency overlaps the ghist-sum + scan
// phase instead of serializing after the threshold barrier.
__global__ void __launch_bounds__(1024) finalize(const float* __restrict__ y,
                                                 const int* __restrict__ ghist,
                                                 float* __restrict__ out) {
    __shared__ int shist[NBINS];
    __shared__ int wsum[16];
    __shared__ int s_t, s_need;
    const int tid = threadIdx.x;
    const int lane = tid & 63;
    const int wid = tid >> 6;

    // ---- prefetch y early (latency overlaps the histogram phase) ----
    const int base = tid * 16;
    float4 v0 = *(const float4*)(y + base);
    float4 v1 = *(const float4*)(y + base + 4);
    float4 v2 = *(const float4*)(y + base + 8);
    float4 v3 = *(const float4*)(y + base + 12);

    if (tid < NBINS) {
        int s = 0;
        #pragma unroll
        for (int c = 0; c < NCOPIES; ++c) s += ghist[c * NBINS + tid];
        shist[tid] = s;
    }
    __syncthreads();
    // suffix inclusive scan over 256 bins (threads 0..255)
    for (int off = 1; off < NBINS; off <<= 1) {
        int add = 0;
        if (tid < NBINS) add = (tid + off < NBINS) ? shist[tid + off] : 0;
        __syncthreads();
        if (tid < NBINS) shist[tid] += add;
        __syncthreads();
    }
    if (tid < NBINS) {
        int cum = shist[tid];
        int cumnext = (tid + 1 < NBINS) ? shist[tid + 1] : 0;
        if (cum >= K_ACTIVE && cumnext < K_ACTIVE) {
            s_t = tid;
            s_need = K_ACTIVE - cumnext;
        }
    }
    __syncthreads();
    const int t = s_t, need = s_need;

    // per-thread contiguous chunk of 16 rows -> stable index order
    int bins[16];
    int c = 0;
    {
        float4 vv[4] = {v0, v1, v2, v3};
        #pragma unroll
        for (int i = 0; i < 4; ++i) {
            int b0 = min((int)vv[i].x, NBINS - 1), b1 = min((int)vv[i].y, NBINS - 1);
            int b2 = min((int)vv[i].z, NBINS - 1), b3 = min((int)vv[i].w, NBINS - 1);
            bins[i*4+0]=b0; bins[i*4+1]=b1; bins[i*4+2]=b2; bins[i*4+3]=b3;
            c += (b0 == t) + (b1 == t) + (b2 == t) + (b3 == t);
        }
    }
    // wave-level inclusive scan of c
    int inc = c;
    #pragma unroll
    for (int off = 1; off < 64; off <<= 1) {
        int v = __shfl_up(inc, off, 64);
        if (lane >= off) inc += v;
    }
    if (lane == 63) wsum[wid] = inc;
    __syncthreads();
    if (wid == 0 && lane < 16) {
        int v = wsum[lane];
        int s = v;
        #pragma unroll
        for (int off = 1; off < 16; off <<= 1) {
            int u = __shfl_up(s, off, 64);
            if (lane >= off) s += u;
        }
        wsum[lane] = s - v;  // exclusive prefix of wave sums
    }
    __syncthreads();
    int run = wsum[wid] + inc - c;  // exclusive prefix over index-ordered chunks

    #pragma unroll
    for (int i = 0; i < 4; ++i) {
        float o[4];
        #pragma unroll
        for (int j = 0; j < 4; ++j) {
            int b = bins[i * 4 + j];
            float r = 0.f;
            if (b > t) r = 1.f;
            else if (b == t) { if (run < need) r = 1.f; run++; }
            o[j] = r;
        }
        *(float4*)(out + base + i * 4) = make_float4(o[0], o[1], o[2], o[3]);
    }
}

extern "C" void kernel_launch(void* const* d_in, const int* in_sizes, int n_in,
                              void* d_out, int out_size, void* d_ws, size_t ws_size,
                              hipStream_t stream) {
    const float* x     = (const float*)d_in[0];
    const float* ylat  = (const float*)d_in[1];
    const float* w_in  = (const float*)d_in[2];
    const float* w_rec = (const float*)d_in[3];
    float* out = (float*)d_out;

    char* ws = (char*)d_ws;
    int*   hdr   = (int*)ws;
    float* y     = (float*)(ws + 256);
    int*   ghist = (int*)(ws + 256 + (size_t)N * sizeof(float));
    int*   list  = (int*)(ws + 256 + (size_t)N * sizeof(float)
                          + (size_t)NCOPIES * NBINS * sizeof(int));
    size_t used = 256 + (size_t)N * sizeof(float) + (size_t)NCOPIES * NBINS * sizeof(int);
    long long cap_ll = (ws_size > used) ? (long long)((ws_size - used) / sizeof(int)) : 0;
    int cap = (cap_ll > 2LL * N) ? 2 * N : (int)cap_ll;

    build_all<<<1, 1024, 0, stream>>>(x, ylat, hdr, list, ghist, cap);
    spmv_hist<<<N / 8, 256, 0, stream>>>(w_in, w_rec, hdr, list, y, ghist);
    finalize<<<1, 1024, 0, stream>>>(y, ghist, out);
}

// Round 8
// 48.962 us; speedup vs baseline: 1.2333x; 1.0142x over previous
//
#include <hip/hip_runtime.h>

#define N 16384
#define K_ACTIVE 50
#define MAT_BIT (1 << 14)
#define NBINS 256
#define NCOPIES 32

// ws layout:
//   [0, 256)    : int hdr (hdr[0] = clamped active-column count)
//   [256, +64K) : float y[N]
//   [+32K)      : int ghist[NCOPIES][NBINS]
//   [+128K)     : int list[2N] (bit14 selects w_rec)

// Single block. Zero ghist; append active columns via LDS-atomic (order
// arbitrary -- output-invariant: y is an exact order-independent sum of 1.0f,
// and all later stages depend only on y).  [R4 measured-good, verbatim]
__global__ void __launch_bounds__(1024) build_all(const float* __restrict__ x,
                                                  const float* __restrict__ yl,
                                                  int* __restrict__ hdr,
                                                  int* __restrict__ list,
                                                  int* __restrict__ ghist,
                                                  int cap) {
    __shared__ int lcnt;
    const int tid = threadIdx.x;
    if (tid == 0) lcnt = 0;
    for (int i = tid; i < NCOPIES * NBINS; i += 1024) ghist[i] = 0;
    __syncthreads();

    const int base = tid * 16;
    #pragma unroll
    for (int i = 0; i < 4; ++i) {
        float4 a = *(const float4*)(x + base + i * 4);
        float4 b = *(const float4*)(yl + base + i * 4);
        float av[4] = {a.x, a.y, a.z, a.w};
        float bv[4] = {b.x, b.y, b.z, b.w};
        #pragma unroll
        for (int j = 0; j < 4; ++j) {
            if (av[j] > 0.5f) {
                int s = atomicAdd(&lcnt, 1);
                if (s < cap) list[s] = base + i * 4 + j;
            }
            if (bv[j] > 0.5f) {
                int s = atomicAdd(&lcnt, 1);
                if (s < cap) list[s] = (base + i * 4 + j) | MAT_BIT;
            }
        }
    }
    __syncthreads();
    if (tid == 0) hdr[0] = (lcnt < cap) ? lcnt : cap;
}

// 2048 blocks x 256 threads (32 waves/CU) -- R4 measured-best, verbatim.
// [Floor: outstanding scattered loads/CU = (64/RPW waves)*(2*RPW) = 128 for
//  any RPW (R5 null); ~210 MB of 128B granules at ~5 TB/s random-access
//  throughput. Last-block-done fusion toxic (R3: device fences per block).]
__global__ void __launch_bounds__(256) spmv_hist(const float* __restrict__ w_in,
                                                 const float* __restrict__ w_rec,
                                                 const int* __restrict__ hdr,
                                                 const int* __restrict__ list,
                                                 float* __restrict__ y,
                                                 int* __restrict__ ghist) {
    __shared__ int hist[NBINS];
    const int tid = threadIdx.x;
    if (tid < NBINS) hist[tid] = 0;
    const int lane = tid & 63;
    const int wid = tid >> 6;
    const int row0 = blockIdx.x * 8 + wid * 2;
    const size_t off0 = (size_t)row0 * N;
    const int n = hdr[0];

    float s0 = 0.f, s1 = 0.f;
    if (lane < n) {
        int enc = list[lane];
        const float* b = (enc & MAT_BIT) ? w_rec : w_in;
        size_t a = off0 + (size_t)(enc & (N - 1));
        s0 += b[a];
        s1 += b[a + N];
    }
    if (lane + 64 < n) {
        int enc = list[lane + 64];
        const float* b = (enc & MAT_BIT) ? w_rec : w_in;
        size_t a = off0 + (size_t)(enc & (N - 1));
        s0 += b[a];
        s1 += b[a + N];
    }
    for (int e = 128 + lane; e < n; e += 64) {   // rare tail
        int enc = list[e];
        const float* b = (enc & MAT_BIT) ? w_rec : w_in;
        size_t a = off0 + (size_t)(enc & (N - 1));
        s0 += b[a];
        s1 += b[a + N];
    }
    #pragma unroll
    for (int off = 32; off >= 1; off >>= 1) {
        s0 += __shfl_xor(s0, off, 64);
        s1 += __shfl_xor(s1, off, 64);
    }
    __syncthreads();   // hist zeroing complete
    if (lane == 0) {
        y[row0] = s0;
        y[row0 + 1] = s1;
        atomicAdd(&hist[min(max((int)s0, 0), NBINS - 1)], 1);
        atomicAdd(&hist[min(max((int)s1, 0), NBINS - 1)], 1);
    }
    __syncthreads();
    if (tid < NBINS) {
        int c = hist[tid];
        if (c) atomicAdd(&ghist[(blockIdx.x & (NCOPIES - 1)) * NBINS + tid], c);
    }
}

// Single block, 1024 threads. R7 structure (early y prefetch, register bins,
// single output pass) with the 16-barrier suffix scan replaced by a
// single-wave shuffle suffix scan (zero barriers; measured-correct in R6).
__global__ void __launch_bounds__(1024) finalize(const float* __restrict__ y,
                                                 const int* __restrict__ ghist,
                                                 float* __restrict__ out) {
    __shared__ __align__(16) int shist[NBINS];
    __shared__ int wsum[16];
    __shared__ int s_t, s_need;
    const int tid = threadIdx.x;
    const int lane = tid & 63;
    const int wid = tid >> 6;

    // ---- prefetch y early (latency overlaps the histogram phase) ----
    const int base = tid * 16;
    float4 v0 = *(const float4*)(y + base);
    float4 v1 = *(const float4*)(y + base + 4);
    float4 v2 = *(const float4*)(y + base + 8);
    float4 v3 = *(const float4*)(y + base + 12);

    if (tid < NBINS) {
        int s = 0;
        #pragma unroll
        for (int c = 0; c < NCOPIES; ++c) s += ghist[c * NBINS + tid];
        shist[tid] = s;
    }
    __syncthreads();

    // wave 0: suffix scan over 256 bins, 4 bins/lane, shuffles only
    if (wid == 0) {
        int4 b = *(const int4*)(shist + lane * 4);
        int s3 = b.w;
        int s2 = b.z + s3;
        int s1 = b.y + s2;
        int s0 = b.x + s1;           // lane-local inclusive suffix sums
        int T = s0;
        int acc = T;
        #pragma unroll
        for (int off = 1; off < 64; off <<= 1) {
            int v = __shfl_down(acc, off, 64);
            if (lane + off < 64) acc += v;
        }
        int above = acc - T;          // sum over bins >= 4*(lane+1)
        int c[4]  = {s0 + above, s1 + above, s2 + above, s3 + above};
        int cn[4] = {s1 + above, s2 + above, s3 + above, above};
        #pragma unroll
        for (int k = 0; k < 4; ++k) {
            if (c[k] >= K_ACTIVE && cn[k] < K_ACTIVE) {
                s_t = lane * 4 + k;           // exactly one (lane,k) matches
                s_need = K_ACTIVE - cn[k];
            }
        }
    }
    __syncthreads();
    const int t = s_t, need = s_need;

    // per-thread contiguous chunk of 16 rows -> stable index order
    int bins[16];
    int c = 0;
    {
        float4 vv[4] = {v0, v1, v2, v3};
        #pragma unroll
        for (int i = 0; i < 4; ++i) {
            int b0 = min((int)vv[i].x, NBINS - 1), b1 = min((int)vv[i].y, NBINS - 1);
            int b2 = min((int)vv[i].z, NBINS - 1), b3 = min((int)vv[i].w, NBINS - 1);
            bins[i*4+0]=b0; bins[i*4+1]=b1; bins[i*4+2]=b2; bins[i*4+3]=b3;
            c += (b0 == t) + (b1 == t) + (b2 == t) + (b3 == t);
        }
    }
    // wave-level inclusive scan of c
    int inc = c;
    #pragma unroll
    for (int off = 1; off < 64; off <<= 1) {
        int v = __shfl_up(inc, off, 64);
        if (lane >= off) inc += v;
    }
    if (lane == 63) wsum[wid] = inc;
    __syncthreads();
    if (wid == 0 && lane < 16) {
        int v = wsum[lane];
        int s = v;
        #pragma unroll
        for (int off = 1; off < 16; off <<= 1) {
            int u = __shfl_up(s, off, 64);
            if (lane >= off) s += u;
        }
        wsum[lane] = s - v;  // exclusive prefix of wave sums
    }
    __syncthreads();
    int run = wsum[wid] + inc - c;  // exclusive prefix over index-ordered chunks

    #pragma unroll
    for (int i = 0; i < 4; ++i) {
        float o[4];
        #pragma unroll
        for (int j = 0; j < 4; ++j) {
            int b = bins[i * 4 + j];
            float r = 0.f;
            if (b > t) r = 1.f;
            else if (b == t) { if (run < need) r = 1.f; run++; }
            o[j] = r;
        }
        *(float4*)(out + base + i * 4) = make_float4(o[0], o[1], o[2], o[3]);
    }
}

extern "C" void kernel_launch(void* const* d_in, const int* in_sizes, int n_in,
                              void* d_out, int out_size, void* d_ws, size_t ws_size,
                              hipStream_t stream) {
    const float* x     = (const float*)d_in[0];
    const float* ylat  = (const float*)d_in[1];
    const float* w_in  = (const float*)d_in[2];
    const float* w_rec = (const float*)d_in[3];
    float* out = (float*)d_out;

    char* ws = (char*)d_ws;
    int*   hdr   = (int*)ws;
    float* y     = (float*)(ws + 256);
    int*   ghist = (int*)(ws + 256 + (size_t)N * sizeof(float));
    int*   list  = (int*)(ws + 256 + (size_t)N * sizeof(float)
                          + (size_t)NCOPIES * NBINS * sizeof(int));
    size_t used = 256 + (size_t)N * sizeof(float) + (size_t)NCOPIES * NBINS * sizeof(int);
    long long cap_ll = (ws_size > used) ? (long long)((ws_size - used) / sizeof(int)) : 0;
    int cap = (cap_ll > 2LL * N) ? 2 * N : (int)cap_ll;

    build_all<<<1, 1024, 0, stream>>>(x, ylat, hdr, list, ghist, cap);
    spmv_hist<<<N / 8, 256, 0, stream>>>(w_in, w_rec, hdr, list, y, ghist);
    finalize<<<1, 1024, 0, stream>>>(y, ghist, out);
}